// Round 22
// baseline (253.636 us; speedup 1.0000x reference)
//
#include <hip/hip_runtime.h>
#include <hip/hip_fp16.h>
#include <math.h>

// ---------------------------------------------------------------------------
// GATv2 x2 + mean-pool + linear, MI355X.
// R22: (1) xr back to fp32 (R21's fp16 xr cost ~6us in the aggs for a
//      marginal byte saving). Keep R21's partition-4 fill (FETCH 31.6->19.2MB,
//      fill 53.5->49.7us). (2) aggregate processes 2 ADJACENT nodes per wave
//      with merged ILP: aggs are latency-bound (102MB random gathers @ 2TB/s,
//      VALU ~3us) -> double in-flight gathers per wave (4/step). VGPR budget
//      ~56-60, under the 64 cliff -> occupancy unchanged, MLP 2x.
// ---------------------------------------------------------------------------

#define ELLC    48
#define OVF_CAP 65536
#define ECHUNK  2048          // edges per fill virtual block

typedef int      vint4 __attribute__((ext_vector_type(4)));
typedef _Float16 half4 __attribute__((ext_vector_type(4)));

// ---------------- slim dual GEMM body: xl = fp16(X*Wl+bl), xr = X*Wr+br ---
#define GROWS 32
template <typename T>
__device__ __forceinline__ void dual_gemm_slim(
    int bid, int t,
    const T* __restrict__ X,
    const float* __restrict__ Wl, const float* __restrict__ bl,
    const float* __restrict__ Wr, const float* __restrict__ br,
    _Float16* __restrict__ xl, float* __restrict__ xr, int n,
    float* xS) {
    int row0 = bid * GROWS;
    for (int i = t; i < GROWS * 16; i += 256) {
        int r = row0 + (i >> 4);
        float4 v = make_float4(0.f, 0.f, 0.f, 0.f);
        if (r < n) {
            if constexpr (sizeof(T) == 2) {
                half4 hv = ((const half4*)(X + (size_t)r * 64))[i & 15];
                v = make_float4((float)hv[0], (float)hv[1], (float)hv[2], (float)hv[3]);
            } else {
                v = ((const float4*)(X + (size_t)r * 64))[i & 15];
            }
        }
        ((float4*)xS)[i] = v;
    }
    __syncthreads();
    int h  = t & 63;
    int rb = t >> 6;  // 0..3
    float accl[8], accr[8];
#pragma unroll
    for (int i = 0; i < 8; ++i) { accl[i] = 0.f; accr[i] = 0.f; }
#pragma unroll 4
    for (int d = 0; d < 64; ++d) {
        float wl = Wl[d * 64 + h];   // coalesced 256B, L2-hot
        float wr = Wr[d * 64 + h];
#pragma unroll
        for (int i = 0; i < 8; ++i) {
            float xv = xS[(rb + 4 * i) * 64 + d];  // wave-uniform broadcast
            accl[i] += xv * wl;
            accr[i] += xv * wr;
        }
    }
    float blv = bl[h], brv = br[h];
#pragma unroll
    for (int i = 0; i < 8; ++i) {
        int r = row0 + rb + 4 * i;
        if (r < n) {
            xl[(size_t)r * 64 + h] = (_Float16)(accl[i] + blv);  // 2B coalesced
            xr[(size_t)r * 64 + h] = accr[i] + brv;
        }
    }
    __syncthreads();
}

__global__ __launch_bounds__(256) void dual_gemm64_f16_kernel(
    const _Float16* __restrict__ X,
    const float* __restrict__ Wl, const float* __restrict__ bl,
    const float* __restrict__ Wr, const float* __restrict__ br,
    _Float16* __restrict__ xl, float* __restrict__ xr, int n) {
    __shared__ float xS[GROWS * 64];
    dual_gemm_slim<_Float16>(blockIdx.x, threadIdx.x, X, Wl, bl, Wr, br,
                             xl, xr, n, xS);
}

// ---------------- interleaved: 4-partition ELL fill + layer-1 GEMM --------
// 16-block groups: r = b%16. r<8 -> fill vb = (b/16)*8+r; partition vb&3 = r&3
// (block XCD = b%8 = r, so partition p served only from XCDs {p, p+4}).
// r>=8 -> gemm vg = (b/16)*8 + (r-8).
__global__ __launch_bounds__(256) void fill_gemm_kernel(
    const int* __restrict__ src, const int* __restrict__ dst,
    int* __restrict__ cnt, unsigned short* __restrict__ ell,
    int* __restrict__ novf, int* __restrict__ ovf_dst, int* __restrict__ ovf_src,
    int E, int N, int psize, int fb, int ggrid,
    const float* __restrict__ X,
    const float* __restrict__ Wl, const float* __restrict__ bl,
    const float* __restrict__ Wr, const float* __restrict__ br,
    _Float16* __restrict__ xl, float* __restrict__ xr) {
    __shared__ float xS[GROWS * 64];
    int b = blockIdx.x;
    int q = b / 16, r = b % 16;
    if (r >= 8) {
        int vg = q * 8 + (r - 8);
        if (vg < ggrid)
            dual_gemm_slim<float>(vg, threadIdx.x, X, Wl, bl, Wr, br,
                                  xl, xr, N, xS);
        return;
    }
    int vb = q * 8 + r;
    if (vb >= fb) return;
    int t     = threadIdx.x;
    int chunk = vb >> 2;
    int p     = vb & 3;                   // partition (2 XCDs per partition)
    int d0    = p * psize;
    int d1    = min(N, d0 + psize);
    int e0    = chunk * ECHUNK;
    int e1    = min(E, e0 + ECHUNK);
    int nq    = (e1 - e0) >> 2;
    const vint4* dst4 = (const vint4*)(dst + e0);
    const vint4* src4 = (const vint4*)(src + e0);

    auto scatter4 = [&](vint4 dv, vint4 sv) {
#pragma unroll
        for (int k = 0; k < 4; ++k) {
            int d = dv[k];
            int s = sv[k];
            if (d >= d0 && d < d1) {
                int pos = atomicAdd(&cnt[d], 1);
                if (pos < ELLC) {
                    ell[d * ELLC + pos] = (unsigned short)s;
                } else {  // P(deg>48) ~ 5e-11 per node
                    int j = atomicAdd(novf, 1);
                    if (j < OVF_CAP) { ovf_dst[j] = d; ovf_src[j] = s; }
                }
            }
        }
    };

    if (nq == (ECHUNK >> 2)) {   // full chunk: both loads up front, 8 chains
        vint4 dvA = __builtin_nontemporal_load(&dst4[t]);
        vint4 svA = __builtin_nontemporal_load(&src4[t]);
        vint4 dvB = __builtin_nontemporal_load(&dst4[t + 256]);
        vint4 svB = __builtin_nontemporal_load(&src4[t + 256]);
        scatter4(dvA, svA);
        scatter4(dvB, svB);
    } else {
        for (int qq = t; qq < nq; qq += 256) {
            vint4 dv = __builtin_nontemporal_load(&dst4[qq]);
            vint4 sv = __builtin_nontemporal_load(&src4[qq]);
            scatter4(dv, sv);
        }
        for (int e = e0 + (nq << 2) + t; e < e1; e += 256) {  // E % 4 tail
            int d = dst[e];
            if (d >= d0 && d < d1) {
                int pos = atomicAdd(&cnt[d], 1);
                int s   = src[e];
                if (pos < ELLC) {
                    ell[d * ELLC + pos] = (unsigned short)s;
                } else {
                    int j = atomicAdd(novf, 1);
                    if (j < OVF_CAP) { ovf_dst[j] = d; ovf_src[j] = s; }
                }
            }
        }
    }
}

// ---------------- per-dst GATv2 aggregation (TWO nodes per wave) ----------
// wave = 4 groups x 16 lanes handles adjacent nodes d0=2*wid, d1=d0+1 with
// merged ILP: 4 independent gathers per k-step (2 per node).
__global__ __launch_bounds__(256) void gat_aggregate_kernel(
    const _Float16* __restrict__ xl, const float* __restrict__ xr,
    const int* __restrict__ cnt, const unsigned short* __restrict__ ell,
    const int* __restrict__ novf, const int* __restrict__ ovf_dst,
    const int* __restrict__ ovf_src,
    const float* __restrict__ att, const float* __restrict__ bias,
    _Float16* __restrict__ out, int n) {
    int wid  = (blockIdx.x * blockDim.x + threadIdx.x) >> 6;
    int lane = threadIdx.x & 63;
    int d0 = wid * 2, d1 = d0 + 1;
    if (d0 >= n) return;
    bool has1 = (d1 < n);
    int g = lane >> 4;   // slot group
    int l = lane & 15;   // feature quad

    float4 att4 = ((const float4*)att)[l];
    float4 b4   = ((const float4*)bias)[l];
    int deg0 = cnt[d0];
    int deg1 = has1 ? cnt[d1] : 0;
    int nd0 = min(deg0, ELLC), nd1 = min(deg1, ELLC);

    // preload both ELL rows (two coalesced 96B reads, independent)
    int my0 = 0, my1 = 0;
    if (lane < ELLC) {
        my0 = (int)ell[d0 * ELLC + lane];
        if (has1) my1 = (int)ell[d1 * ELLC + lane];
    }
    int f0 = (deg0 > 0) ? __shfl(my0, 0) : 0;
    int f1 = (deg1 > 0) ? __shfl(my1, 0) : 0;

    float4 xr40 = ((const float4*)(xr + (size_t)d0 * 64))[l];
    float4 xr41 = has1 ? ((const float4*)(xr + (size_t)d1 * 64))[l]
                       : make_float4(0.f, 0.f, 0.f, 0.f);

    float  s0 = 0.f, s1 = 0.f;
    float4 a0 = make_float4(0.f, 0.f, 0.f, 0.f);
    float4 a1 = make_float4(0.f, 0.f, 0.f, 0.f);
    int ndmax = max(nd0, nd1);

#pragma unroll 6
    for (int k = 0; k * 8 < ndmax; ++k) {    // wave-uniform
        int  sa  = k * 8 + g, sb = sa + 4;
        bool a00 = sa < nd0, a01 = sb < nd0;
        bool a10 = sa < nd1, a11 = sb < nd1;
        int i00 = __shfl(my0, sa); if (!a00) i00 = f0;
        int i01 = __shfl(my0, sb); if (!a01) i01 = f0;
        int i10 = __shfl(my1, sa); if (!a10) i10 = f1;
        int i11 = __shfl(my1, sb); if (!a11) i11 = f1;
        half4 h00 = ((const half4*)(xl + (size_t)i00 * 64))[l];  // 4 gathers
        half4 h01 = ((const half4*)(xl + (size_t)i01 * 64))[l];  //  in flight
        half4 h10 = ((const half4*)(xl + (size_t)i10 * 64))[l];
        half4 h11 = ((const half4*)(xl + (size_t)i11 * 64))[l];
        float4 x00 = make_float4((float)h00[0], (float)h00[1], (float)h00[2], (float)h00[3]);
        float4 x01 = make_float4((float)h01[0], (float)h01[1], (float)h01[2], (float)h01[3]);
        float4 x10 = make_float4((float)h10[0], (float)h10[1], (float)h10[2], (float)h10[3]);
        float4 x11 = make_float4((float)h11[0], (float)h11[1], (float)h11[2], (float)h11[3]);
        float z, c00 = 0.f, c01 = 0.f, c10 = 0.f, c11 = 0.f;
        z = x00.x + xr40.x; c00 += ((z > 0.f) ? z : 0.2f * z) * att4.x;
        z = x00.y + xr40.y; c00 += ((z > 0.f) ? z : 0.2f * z) * att4.y;
        z = x00.z + xr40.z; c00 += ((z > 0.f) ? z : 0.2f * z) * att4.z;
        z = x00.w + xr40.w; c00 += ((z > 0.f) ? z : 0.2f * z) * att4.w;
        z = x01.x + xr40.x; c01 += ((z > 0.f) ? z : 0.2f * z) * att4.x;
        z = x01.y + xr40.y; c01 += ((z > 0.f) ? z : 0.2f * z) * att4.y;
        z = x01.z + xr40.z; c01 += ((z > 0.f) ? z : 0.2f * z) * att4.z;
        z = x01.w + xr40.w; c01 += ((z > 0.f) ? z : 0.2f * z) * att4.w;
        z = x10.x + xr41.x; c10 += ((z > 0.f) ? z : 0.2f * z) * att4.x;
        z = x10.y + xr41.y; c10 += ((z > 0.f) ? z : 0.2f * z) * att4.y;
        z = x10.z + xr41.z; c10 += ((z > 0.f) ? z : 0.2f * z) * att4.z;
        z = x10.w + xr41.w; c10 += ((z > 0.f) ? z : 0.2f * z) * att4.w;
        z = x11.x + xr41.x; c11 += ((z > 0.f) ? z : 0.2f * z) * att4.x;
        z = x11.y + xr41.y; c11 += ((z > 0.f) ? z : 0.2f * z) * att4.y;
        z = x11.z + xr41.z; c11 += ((z > 0.f) ? z : 0.2f * z) * att4.z;
        z = x11.w + xr41.w; c11 += ((z > 0.f) ? z : 0.2f * z) * att4.w;
#pragma unroll
        for (int sh = 8; sh >= 1; sh >>= 1) {  // 4 interleaved 16-lane reduces
            c00 += __shfl_xor(c00, sh);
            c01 += __shfl_xor(c01, sh);
            c10 += __shfl_xor(c10, sh);
            c11 += __shfl_xor(c11, sh);
        }
        float w00 = a00 ? __expf(fminf(c00, 30.f)) : 0.f;
        float w01 = a01 ? __expf(fminf(c01, 30.f)) : 0.f;
        float w10 = a10 ? __expf(fminf(c10, 30.f)) : 0.f;
        float w11 = a11 ? __expf(fminf(c11, 30.f)) : 0.f;
        s0 += w00 + w01;
        s1 += w10 + w11;
        a0.x += w00 * x00.x + w01 * x01.x;
        a0.y += w00 * x00.y + w01 * x01.y;
        a0.z += w00 * x00.z + w01 * x01.z;
        a0.w += w00 * x00.w + w01 * x01.w;
        a1.x += w10 * x10.x + w11 * x11.x;
        a1.y += w10 * x10.y + w11 * x11.y;
        a1.z += w10 * x10.z + w11 * x11.z;
        a1.w += w10 * x10.w + w11 * x11.w;
    }
    // overflow fold (deg > ELLC): scan tiny global list; empty in practice
    if (deg0 > ELLC || deg1 > ELLC) {
        int no = min(*novf, OVF_CAP);
        for (int j = g; j < no; j += 4) {
            int od = ovf_dst[j];
            bool m0 = (od == d0), m1 = (od == d1);
            if (!(m0 || m1)) continue;
            int  i0 = ovf_src[j];
            half4 h0 = ((const half4*)(xl + (size_t)i0 * 64))[l];
            float4 x0 = make_float4((float)h0[0], (float)h0[1], (float)h0[2], (float)h0[3]);
            float4 xrr = m0 ? xr40 : xr41;
            float z, c0 = 0.f;
            z = x0.x + xrr.x; c0 += ((z > 0.f) ? z : 0.2f * z) * att4.x;
            z = x0.y + xrr.y; c0 += ((z > 0.f) ? z : 0.2f * z) * att4.y;
            z = x0.z + xrr.z; c0 += ((z > 0.f) ? z : 0.2f * z) * att4.z;
            z = x0.w + xrr.w; c0 += ((z > 0.f) ? z : 0.2f * z) * att4.w;
#pragma unroll
            for (int sh = 8; sh >= 1; sh >>= 1) c0 += __shfl_xor(c0, sh);
            float w0 = __expf(fminf(c0, 30.f));
            if (m0) {
                s0 += w0;
                a0.x += w0 * x0.x; a0.y += w0 * x0.y;
                a0.z += w0 * x0.z; a0.w += w0 * x0.w;
            } else {
                s1 += w0;
                a1.x += w0 * x0.x; a1.y += w0 * x0.y;
                a1.z += w0 * x0.z; a1.w += w0 * x0.w;
            }
        }
    }
    // NOTE: overflow fold above diverges per-group (continue); safe because
    // shuffles inside only span the 16-lane group which shares the same j.
    // merge the 4 group partial sums for both nodes
#pragma unroll
    for (int mask = 16; mask <= 32; mask <<= 1) {
        s0   += __shfl_xor(s0, mask);
        s1   += __shfl_xor(s1, mask);
        a0.x += __shfl_xor(a0.x, mask);
        a0.y += __shfl_xor(a0.y, mask);
        a0.z += __shfl_xor(a0.z, mask);
        a0.w += __shfl_xor(a0.w, mask);
        a1.x += __shfl_xor(a1.x, mask);
        a1.y += __shfl_xor(a1.y, mask);
        a1.z += __shfl_xor(a1.z, mask);
        a1.w += __shfl_xor(a1.w, mask);
    }
    if (g == 0) {
        float inv0 = (s0 > 0.f) ? (1.f / s0) : 0.f;   // deg-0 -> relu(bias)
        half4 hv;
        hv[0] = (_Float16)fmaxf(a0.x * inv0 + b4.x, 0.f);
        hv[1] = (_Float16)fmaxf(a0.y * inv0 + b4.y, 0.f);
        hv[2] = (_Float16)fmaxf(a0.z * inv0 + b4.z, 0.f);
        hv[3] = (_Float16)fmaxf(a0.w * inv0 + b4.w, 0.f);
        ((half4*)(out + (size_t)d0 * 64))[l] = hv;
        if (has1) {
            float inv1 = (s1 > 0.f) ? (1.f / s1) : 0.f;
            half4 hw;
            hw[0] = (_Float16)fmaxf(a1.x * inv1 + b4.x, 0.f);
            hw[1] = (_Float16)fmaxf(a1.y * inv1 + b4.y, 0.f);
            hw[2] = (_Float16)fmaxf(a1.z * inv1 + b4.z, 0.f);
            hw[3] = (_Float16)fmaxf(a1.w * inv1 + b4.w, 0.f);
            ((half4*)(out + (size_t)d1 * 64))[l] = hw;
        }
    }
}

// ---------------- per-graph mean pool + final linear (no atomics) ---------
__global__ __launch_bounds__(256) void pool_final_kernel(
    const _Float16* __restrict__ h, const int* __restrict__ batch,
    const float* __restrict__ lin_w, const float* __restrict__ lin_b,
    float* __restrict__ out, int N, int G) {
    int g = blockIdx.x;
    int t = threadIdx.x;
    auto lb = [&](int key) {
        int lo = 0, hi = N;
        while (lo < hi) {
            int mid = (lo + hi) >> 1;
            if (batch[mid] < key) lo = mid + 1; else hi = mid;
        }
        return lo;
    };
    int start = lb(g), end = lb(g + 1);

    __shared__ float part[4][64];
    __shared__ float pooled[64];
    int f = t & 63, w = t >> 6;
    float acc = 0.f;
    for (int i = start + w; i < end; i += 4)
        acc += (float)h[(size_t)i * 64 + f];
    part[w][f] = acc;
    __syncthreads();
    if (t < 64) {
        float s = part[0][t] + part[1][t] + part[2][t] + part[3][t];
        pooled[t] = s / fmaxf((float)(end - start), 1.f);
    }
    __syncthreads();
    if (t < 32) {
        float a = 0.f;
#pragma unroll 8
        for (int hh = 0; hh < 64; ++hh) a += pooled[hh] * lin_w[hh * 32 + t];
        out[g * 32 + t] = a + lin_b[t];
    }
}

extern "C" void kernel_launch(void* const* d_in, const int* in_sizes, int n_in,
                              void* d_out, int out_size, void* d_ws, size_t ws_size,
                              hipStream_t stream) {
    const float* x     = (const float*)d_in[0];
    const int*   ei    = (const int*)d_in[1];
    const int*   batch = (const int*)d_in[2];
    const float* Wl1   = (const float*)d_in[3];
    const float* bl1   = (const float*)d_in[4];
    const float* Wr1   = (const float*)d_in[5];
    const float* br1   = (const float*)d_in[6];
    const float* att1  = (const float*)d_in[7];
    const float* bias1 = (const float*)d_in[8];
    const float* Wl2   = (const float*)d_in[9];
    const float* bl2   = (const float*)d_in[10];
    const float* Wr2   = (const float*)d_in[11];
    const float* br2   = (const float*)d_in[12];
    const float* att2  = (const float*)d_in[13];
    const float* bias2 = (const float*)d_in[14];
    const float* lin_w = (const float*)d_in[15];
    const float* lin_b = (const float*)d_in[16];
    float* out = (float*)d_out;

    const int N = in_sizes[0] / 64;
    const int E = in_sizes[1] / 2;
    const int G = out_size / 32;
    const int* src = ei;
    const int* dst = ei + E;

    // ---- workspace carve-up (256B-aligned) ----
    char*  ws  = (char*)d_ws;
    size_t off = 0;
    auto alloc = [&](size_t bytes) -> void* {
        void* p = ws + off;
        off += bytes;
        off = (off + 255) & ~(size_t)255;
        return p;
    };
    _Float16* xl   = (_Float16*)alloc((size_t)N * 64 * sizeof(_Float16));
    float* xr      = (float*)alloc((size_t)N * 64 * sizeof(float));
    _Float16* h1   = (_Float16*)alloc((size_t)N * 64 * sizeof(_Float16));  // h1/h2
    // zeroed region (contiguous): cnt, novf
    int*   cnt     = (int*)alloc((size_t)N * sizeof(int));
    int*   novf    = (int*)alloc(256);
    char*  zend    = ws + off;
    unsigned short* ell = (unsigned short*)alloc((size_t)N * ELLC * sizeof(unsigned short));
    int*   ovf_dst = (int*)alloc((size_t)OVF_CAP * sizeof(int));
    int*   ovf_src = (int*)alloc((size_t)OVF_CAP * sizeof(int));

    (void)hipMemsetAsync(cnt, 0, (size_t)(zend - (char*)cnt), stream);

    int ggrid  = (N + GROWS - 1) / GROWS;
    int agrid  = (N + 7) / 8;                    // 4 waves/block, 2 nodes/wave
    int nchunk = (E + ECHUNK - 1) / ECHUNK;
    int fb     = nchunk * 4;                     // fill virtual blocks (x4 part)
    int psize  = (N + 3) / 4;                    // dst partition size
    // interleaved grid: groups of 16 = 8 fill + 8 gemm
    int ngroups = max((fb + 7) / 8, (ggrid + 7) / 8);
    int igrid   = ngroups * 16;

    // ---- interleaved: 4-partition ELL fill + layer-1 dual GEMM ----
    fill_gemm_kernel<<<igrid, 256, 0, stream>>>(
        src, dst, cnt, ell, novf, ovf_dst, ovf_src, E, N, psize, fb, ggrid,
        x, Wl1, bl1, Wr1, br1, xl, xr);

    // ---- agg1 -> h1 (fp16), 2 nodes/wave ----
    gat_aggregate_kernel<<<agrid, 256, 0, stream>>>(
        xl, xr, cnt, ell, novf, ovf_dst, ovf_src, att1, bias1, h1, N);

    // ---- layer 2 GEMM (fp16 input; h1 consumed, xl/xr overwritten) ----
    dual_gemm64_f16_kernel<<<ggrid, 256, 0, stream>>>(
        h1, Wl2, bl2, Wr2, br2, xl, xr, N);

    // ---- agg2 -> h1 (fp16, reused) ----
    gat_aggregate_kernel<<<agrid, 256, 0, stream>>>(
        xl, xr, cnt, ell, novf, ovf_dst, ovf_src, att2, bias2, h1, N);

    // ---- per-graph pool + final linear (one dispatch, no atomics) ----
    pool_final_kernel<<<G, 256, 0, stream>>>(h1, batch, lin_w, lin_b, out, N, G);
}

// Round 23
// 243.959 us; speedup vs baseline: 1.0397x; 1.0397x over previous
//
#include <hip/hip_runtime.h>
#include <hip/hip_fp16.h>
#include <math.h>

// ---------------------------------------------------------------------------
// GATv2 x2 + mean-pool + linear, MI355X.
// R23: compose verified best. R20 base (243.4us: one-wave-per-dst agg with
//      fp32 xr + fp16 xl/h, interleaved fill/gemm1, per-graph pool_final)
//      + R21/R22's partition-4 fill (53.5->50.8us, FETCH 31.6->19.3MB).
//      R22 lesson: 2-node-per-wave agg pays E[max(P16,P16)]~18.3 steps for
//      both nodes + 2x VALU; TLP already hides latency -> reverted.
// ---------------------------------------------------------------------------

#define ELLC    48
#define OVF_CAP 65536
#define ECHUNK  2048          // edges per fill virtual block

typedef int      vint4 __attribute__((ext_vector_type(4)));
typedef _Float16 half4 __attribute__((ext_vector_type(4)));

// ---------------- slim dual GEMM body: xl = fp16(X*Wl+bl), xr = X*Wr+br ---
#define GROWS 32
template <typename T>
__device__ __forceinline__ void dual_gemm_slim(
    int bid, int t,
    const T* __restrict__ X,
    const float* __restrict__ Wl, const float* __restrict__ bl,
    const float* __restrict__ Wr, const float* __restrict__ br,
    _Float16* __restrict__ xl, float* __restrict__ xr, int n,
    float* xS) {
    int row0 = bid * GROWS;
    for (int i = t; i < GROWS * 16; i += 256) {
        int r = row0 + (i >> 4);
        float4 v = make_float4(0.f, 0.f, 0.f, 0.f);
        if (r < n) {
            if constexpr (sizeof(T) == 2) {
                half4 hv = ((const half4*)(X + (size_t)r * 64))[i & 15];
                v = make_float4((float)hv[0], (float)hv[1], (float)hv[2], (float)hv[3]);
            } else {
                v = ((const float4*)(X + (size_t)r * 64))[i & 15];
            }
        }
        ((float4*)xS)[i] = v;
    }
    __syncthreads();
    int h  = t & 63;
    int rb = t >> 6;  // 0..3
    float accl[8], accr[8];
#pragma unroll
    for (int i = 0; i < 8; ++i) { accl[i] = 0.f; accr[i] = 0.f; }
#pragma unroll 4
    for (int d = 0; d < 64; ++d) {
        float wl = Wl[d * 64 + h];   // coalesced 256B, L2-hot
        float wr = Wr[d * 64 + h];
#pragma unroll
        for (int i = 0; i < 8; ++i) {
            float xv = xS[(rb + 4 * i) * 64 + d];  // wave-uniform broadcast
            accl[i] += xv * wl;
            accr[i] += xv * wr;
        }
    }
    float blv = bl[h], brv = br[h];
#pragma unroll
    for (int i = 0; i < 8; ++i) {
        int r = row0 + rb + 4 * i;
        if (r < n) {
            xl[(size_t)r * 64 + h] = (_Float16)(accl[i] + blv);  // 2B coalesced
            xr[(size_t)r * 64 + h] = accr[i] + brv;
        }
    }
    __syncthreads();
}

__global__ __launch_bounds__(256) void dual_gemm64_f16_kernel(
    const _Float16* __restrict__ X,
    const float* __restrict__ Wl, const float* __restrict__ bl,
    const float* __restrict__ Wr, const float* __restrict__ br,
    _Float16* __restrict__ xl, float* __restrict__ xr, int n) {
    __shared__ float xS[GROWS * 64];
    dual_gemm_slim<_Float16>(blockIdx.x, threadIdx.x, X, Wl, bl, Wr, br,
                             xl, xr, n, xS);
}

// ---------------- interleaved: 4-partition ELL fill + layer-1 GEMM --------
// 16-block groups: r = b%16. r<8 -> fill vb = (b/16)*8+r; partition vb&3 = r&3
// (block XCD = b%8 = r, so partition p served only from XCDs {p, p+4}).
// r>=8 -> gemm vg = (b/16)*8 + (r-8).
__global__ __launch_bounds__(256) void fill_gemm_kernel(
    const int* __restrict__ src, const int* __restrict__ dst,
    int* __restrict__ cnt, unsigned short* __restrict__ ell,
    int* __restrict__ novf, int* __restrict__ ovf_dst, int* __restrict__ ovf_src,
    int E, int N, int psize, int fb, int ggrid,
    const float* __restrict__ X,
    const float* __restrict__ Wl, const float* __restrict__ bl,
    const float* __restrict__ Wr, const float* __restrict__ br,
    _Float16* __restrict__ xl, float* __restrict__ xr) {
    __shared__ float xS[GROWS * 64];
    int b = blockIdx.x;
    int q = b / 16, r = b % 16;
    if (r >= 8) {
        int vg = q * 8 + (r - 8);
        if (vg < ggrid)
            dual_gemm_slim<float>(vg, threadIdx.x, X, Wl, bl, Wr, br,
                                  xl, xr, N, xS);
        return;
    }
    int vb = q * 8 + r;
    if (vb >= fb) return;
    int t     = threadIdx.x;
    int chunk = vb >> 2;
    int p     = vb & 3;                   // partition (2 XCDs per partition)
    int d0    = p * psize;
    int d1    = min(N, d0 + psize);
    int e0    = chunk * ECHUNK;
    int e1    = min(E, e0 + ECHUNK);
    int nq    = (e1 - e0) >> 2;
    const vint4* dst4 = (const vint4*)(dst + e0);
    const vint4* src4 = (const vint4*)(src + e0);

    auto scatter4 = [&](vint4 dv, vint4 sv) {
#pragma unroll
        for (int k = 0; k < 4; ++k) {
            int d = dv[k];
            int s = sv[k];
            if (d >= d0 && d < d1) {
                int pos = atomicAdd(&cnt[d], 1);
                if (pos < ELLC) {
                    ell[d * ELLC + pos] = (unsigned short)s;
                } else {  // P(deg>48) ~ 5e-11 per node
                    int j = atomicAdd(novf, 1);
                    if (j < OVF_CAP) { ovf_dst[j] = d; ovf_src[j] = s; }
                }
            }
        }
    };

    if (nq == (ECHUNK >> 2)) {   // full chunk: both loads up front, 8 chains
        vint4 dvA = __builtin_nontemporal_load(&dst4[t]);
        vint4 svA = __builtin_nontemporal_load(&src4[t]);
        vint4 dvB = __builtin_nontemporal_load(&dst4[t + 256]);
        vint4 svB = __builtin_nontemporal_load(&src4[t + 256]);
        scatter4(dvA, svA);
        scatter4(dvB, svB);
    } else {
        for (int qq = t; qq < nq; qq += 256) {
            vint4 dv = __builtin_nontemporal_load(&dst4[qq]);
            vint4 sv = __builtin_nontemporal_load(&src4[qq]);
            scatter4(dv, sv);
        }
        for (int e = e0 + (nq << 2) + t; e < e1; e += 256) {  // E % 4 tail
            int d = dst[e];
            if (d >= d0 && d < d1) {
                int pos = atomicAdd(&cnt[d], 1);
                int s   = src[e];
                if (pos < ELLC) {
                    ell[d * ELLC + pos] = (unsigned short)s;
                } else {
                    int j = atomicAdd(novf, 1);
                    if (j < OVF_CAP) { ovf_dst[j] = d; ovf_src[j] = s; }
                }
            }
        }
    }
}

// ---------------- per-dst GATv2 aggregation (one wave per dst) ------------
// wave = 4 groups x 16 lanes; ELL row preloaded once, indices via __shfl.
// xl fp16, xr fp32 in; h fp16 out.
__global__ __launch_bounds__(256) void gat_aggregate_kernel(
    const _Float16* __restrict__ xl, const float* __restrict__ xr,
    const int* __restrict__ cnt, const unsigned short* __restrict__ ell,
    const int* __restrict__ novf, const int* __restrict__ ovf_dst,
    const int* __restrict__ ovf_src,
    const float* __restrict__ att, const float* __restrict__ bias,
    _Float16* __restrict__ out, int n) {
    int wid  = (blockIdx.x * blockDim.x + threadIdx.x) >> 6;
    int lane = threadIdx.x & 63;
    if (wid >= n) return;
    int g = lane >> 4;   // slot group
    int l = lane & 15;   // feature quad
    int d = wid;

    float4 att4 = ((const float4*)att)[l];
    float4 b4   = ((const float4*)bias)[l];
    int deg_d = cnt[d];
    int nd  = min(deg_d, ELLC);
    int beg = d * ELLC;

    float  s   = 0.f;
    float4 acc = make_float4(0.f, 0.f, 0.f, 0.f);

    if (deg_d > 0) {
        // one coalesced 96B read of the whole ELL row; lane i holds slot i
        int myidx = 0;
        if (lane < ELLC) myidx = (int)ell[beg + lane];
        int i_first = __shfl(myidx, 0);

        float4 xr4 = ((const float4*)(xr + (size_t)d * 64))[l];

#pragma unroll 6
        for (int k = 0; k * 8 < nd; ++k) {     // k < 6 (nd <= 48); uniform
            int  sa = k * 8 + g, sb = sa + 4;
            bool aa = sa < nd,   ab = sb < nd;
            int  i0 = __shfl(myidx, sa); if (!aa) i0 = i_first;
            int  i1 = __shfl(myidx, sb); if (!ab) i1 = i_first;
            half4 h0 = ((const half4*)(xl + (size_t)i0 * 64))[l];  // 8B gather
            half4 h1 = ((const half4*)(xl + (size_t)i1 * 64))[l];
            float4 x0 = make_float4((float)h0[0], (float)h0[1], (float)h0[2], (float)h0[3]);
            float4 x1 = make_float4((float)h1[0], (float)h1[1], (float)h1[2], (float)h1[3]);
            float z, c0 = 0.f, c1 = 0.f;
            z = x0.x + xr4.x; c0 += ((z > 0.f) ? z : 0.2f * z) * att4.x;
            z = x0.y + xr4.y; c0 += ((z > 0.f) ? z : 0.2f * z) * att4.y;
            z = x0.z + xr4.z; c0 += ((z > 0.f) ? z : 0.2f * z) * att4.z;
            z = x0.w + xr4.w; c0 += ((z > 0.f) ? z : 0.2f * z) * att4.w;
            z = x1.x + xr4.x; c1 += ((z > 0.f) ? z : 0.2f * z) * att4.x;
            z = x1.y + xr4.y; c1 += ((z > 0.f) ? z : 0.2f * z) * att4.y;
            z = x1.z + xr4.z; c1 += ((z > 0.f) ? z : 0.2f * z) * att4.z;
            z = x1.w + xr4.w; c1 += ((z > 0.f) ? z : 0.2f * z) * att4.w;
#pragma unroll
            for (int sh = 8; sh >= 1; sh >>= 1) {  // 16-lane reduce
                c0 += __shfl_xor(c0, sh);
                c1 += __shfl_xor(c1, sh);
            }
            float w0 = aa ? __expf(fminf(c0, 30.f)) : 0.f;
            float w1 = ab ? __expf(fminf(c1, 30.f)) : 0.f;
            s += w0 + w1;
            acc.x += w0 * x0.x + w1 * x1.x;
            acc.y += w0 * x0.y + w1 * x1.y;
            acc.z += w0 * x0.z + w1 * x1.z;
            acc.w += w0 * x0.w + w1 * x1.w;
        }
        // overflow fold (deg > ELLC): empty in practice
        if (deg_d > ELLC) {
            int no = min(*novf, OVF_CAP);
            for (int j = g; j < no; j += 4) {
                bool active = (ovf_dst[j] == d);
                int  i0     = active ? ovf_src[j] : i_first;
                half4 h0 = ((const half4*)(xl + (size_t)i0 * 64))[l];
                float4 x0 = make_float4((float)h0[0], (float)h0[1], (float)h0[2], (float)h0[3]);
                float z, c0 = 0.f;
                z = x0.x + xr4.x; c0 += ((z > 0.f) ? z : 0.2f * z) * att4.x;
                z = x0.y + xr4.y; c0 += ((z > 0.f) ? z : 0.2f * z) * att4.y;
                z = x0.z + xr4.z; c0 += ((z > 0.f) ? z : 0.2f * z) * att4.z;
                z = x0.w + xr4.w; c0 += ((z > 0.f) ? z : 0.2f * z) * att4.w;
#pragma unroll
                for (int sh = 8; sh >= 1; sh >>= 1) c0 += __shfl_xor(c0, sh);
                float w0 = active ? __expf(fminf(c0, 30.f)) : 0.f;
                s += w0;
                acc.x += w0 * x0.x;
                acc.y += w0 * x0.y;
                acc.z += w0 * x0.z;
                acc.w += w0 * x0.w;
            }
        }
        // merge the 4 group partial sums, xor 16 then xor 32
#pragma unroll
        for (int mask = 16; mask <= 32; mask <<= 1) {
            s     += __shfl_xor(s, mask);
            acc.x += __shfl_xor(acc.x, mask);
            acc.y += __shfl_xor(acc.y, mask);
            acc.z += __shfl_xor(acc.z, mask);
            acc.w += __shfl_xor(acc.w, mask);
        }
    }
    if (g == 0) {
        float inv = (s > 0.f) ? (1.f / s) : 0.f;   // deg-0 -> relu(bias)
        half4 hv;
        hv[0] = (_Float16)fmaxf(acc.x * inv + b4.x, 0.f);
        hv[1] = (_Float16)fmaxf(acc.y * inv + b4.y, 0.f);
        hv[2] = (_Float16)fmaxf(acc.z * inv + b4.z, 0.f);
        hv[3] = (_Float16)fmaxf(acc.w * inv + b4.w, 0.f);
        ((half4*)(out + (size_t)d * 64))[l] = hv;
    }
}

// ---------------- per-graph mean pool + final linear (no atomics) ---------
// block g = graph g; batch is sorted -> binary search node range.
__global__ __launch_bounds__(256) void pool_final_kernel(
    const _Float16* __restrict__ h, const int* __restrict__ batch,
    const float* __restrict__ lin_w, const float* __restrict__ lin_b,
    float* __restrict__ out, int N, int G) {
    int g = blockIdx.x;
    int t = threadIdx.x;
    auto lb = [&](int key) {
        int lo = 0, hi = N;
        while (lo < hi) {
            int mid = (lo + hi) >> 1;
            if (batch[mid] < key) lo = mid + 1; else hi = mid;
        }
        return lo;
    };
    int start = lb(g), end = lb(g + 1);

    __shared__ float part[4][64];
    __shared__ float pooled[64];
    int f = t & 63, w = t >> 6;
    float acc = 0.f;
    for (int i = start + w; i < end; i += 4)
        acc += (float)h[(size_t)i * 64 + f];
    part[w][f] = acc;
    __syncthreads();
    if (t < 64) {
        float s = part[0][t] + part[1][t] + part[2][t] + part[3][t];
        pooled[t] = s / fmaxf((float)(end - start), 1.f);
    }
    __syncthreads();
    if (t < 32) {
        float a = 0.f;
#pragma unroll 8
        for (int hh = 0; hh < 64; ++hh) a += pooled[hh] * lin_w[hh * 32 + t];
        out[g * 32 + t] = a + lin_b[t];
    }
}

extern "C" void kernel_launch(void* const* d_in, const int* in_sizes, int n_in,
                              void* d_out, int out_size, void* d_ws, size_t ws_size,
                              hipStream_t stream) {
    const float* x     = (const float*)d_in[0];
    const int*   ei    = (const int*)d_in[1];
    const int*   batch = (const int*)d_in[2];
    const float* Wl1   = (const float*)d_in[3];
    const float* bl1   = (const float*)d_in[4];
    const float* Wr1   = (const float*)d_in[5];
    const float* br1   = (const float*)d_in[6];
    const float* att1  = (const float*)d_in[7];
    const float* bias1 = (const float*)d_in[8];
    const float* Wl2   = (const float*)d_in[9];
    const float* bl2   = (const float*)d_in[10];
    const float* Wr2   = (const float*)d_in[11];
    const float* br2   = (const float*)d_in[12];
    const float* att2  = (const float*)d_in[13];
    const float* bias2 = (const float*)d_in[14];
    const float* lin_w = (const float*)d_in[15];
    const float* lin_b = (const float*)d_in[16];
    float* out = (float*)d_out;

    const int N = in_sizes[0] / 64;
    const int E = in_sizes[1] / 2;
    const int G = out_size / 32;
    const int* src = ei;
    const int* dst = ei + E;

    // ---- workspace carve-up (256B-aligned) ----
    char*  ws  = (char*)d_ws;
    size_t off = 0;
    auto alloc = [&](size_t bytes) -> void* {
        void* p = ws + off;
        off += bytes;
        off = (off + 255) & ~(size_t)255;
        return p;
    };
    _Float16* xl   = (_Float16*)alloc((size_t)N * 64 * sizeof(_Float16));
    float* xr      = (float*)alloc((size_t)N * 64 * sizeof(float));
    _Float16* h1   = (_Float16*)alloc((size_t)N * 64 * sizeof(_Float16));  // h1/h2
    // zeroed region (contiguous): cnt, novf
    int*   cnt     = (int*)alloc((size_t)N * sizeof(int));
    int*   novf    = (int*)alloc(256);
    char*  zend    = ws + off;
    unsigned short* ell = (unsigned short*)alloc((size_t)N * ELLC * sizeof(unsigned short));
    int*   ovf_dst = (int*)alloc((size_t)OVF_CAP * sizeof(int));
    int*   ovf_src = (int*)alloc((size_t)OVF_CAP * sizeof(int));

    (void)hipMemsetAsync(cnt, 0, (size_t)(zend - (char*)cnt), stream);

    int ggrid  = (N + GROWS - 1) / GROWS;
    int agrid  = (N + 3) / 4;                    // one wave per dst node
    int nchunk = (E + ECHUNK - 1) / ECHUNK;
    int fb     = nchunk * 4;                     // fill virtual blocks (x4 part)
    int psize  = (N + 3) / 4;                    // dst partition size
    // interleaved grid: groups of 16 = 8 fill + 8 gemm
    int ngroups = max((fb + 7) / 8, (ggrid + 7) / 8);
    int igrid   = ngroups * 16;

    // ---- interleaved: 4-partition ELL fill + layer-1 dual GEMM ----
    fill_gemm_kernel<<<igrid, 256, 0, stream>>>(
        src, dst, cnt, ell, novf, ovf_dst, ovf_src, E, N, psize, fb, ggrid,
        x, Wl1, bl1, Wr1, br1, xl, xr);

    // ---- agg1 -> h1 (fp16) ----
    gat_aggregate_kernel<<<agrid, 256, 0, stream>>>(
        xl, xr, cnt, ell, novf, ovf_dst, ovf_src, att1, bias1, h1, N);

    // ---- layer 2 GEMM (fp16 input; h1 consumed, xl/xr overwritten) ----
    dual_gemm64_f16_kernel<<<ggrid, 256, 0, stream>>>(
        h1, Wl2, bl2, Wr2, br2, xl, xr, N);

    // ---- agg2 -> h1 (fp16, reused) ----
    gat_aggregate_kernel<<<agrid, 256, 0, stream>>>(
        xl, xr, cnt, ell, novf, ovf_dst, ovf_src, att2, bias2, h1, N);

    // ---- per-graph pool + final linear (one dispatch, no atomics) ----
    pool_final_kernel<<<G, 256, 0, stream>>>(h1, batch, lin_w, lin_b, out, N, G);
}